// Round 2
// baseline (806.281 us; speedup 1.0000x reference)
//
#include <hip/hip_runtime.h>

#define NEG_SLOPE 0.2f
#define EPSV 1e-16f

// order-preserving float <-> uint encoding for atomicMax-based segment max
__device__ __forceinline__ unsigned fenc(float f){
  unsigned u = __float_as_uint(f);
  return (u & 0x80000000u) ? ~u : (u | 0x80000000u);
}
__device__ __forceinline__ float fdec(unsigned u){
  return __uint_as_float((u & 0x80000000u) ? (u ^ 0x80000000u) : ~u);
}

// ---------------- CSR build ----------------
__global__ void k_deg(const int* __restrict__ ei, int E, int N, int* __restrict__ deg){
  int t = blockIdx.x*blockDim.x + threadIdx.x;
  int ET = E + N;
  if (t >= ET) return;
  int dst = (t < E) ? ei[E + t] : (t - E);
  atomicAdd(&deg[dst], 1);
}

__global__ void k_scan(const int* __restrict__ deg, int N, int* __restrict__ rs){
  __shared__ int sums[1024];
  int tid = threadIdx.x;
  int chunk = (N + 1023) >> 10;
  int s = tid*chunk, e = min(s+chunk, N);
  int sum = 0;
  for (int i = s; i < e; ++i) sum += deg[i];
  sums[tid] = sum;
  __syncthreads();
  for (int off = 1; off < 1024; off <<= 1){
    int v = (tid >= off) ? sums[tid-off] : 0;
    __syncthreads();
    sums[tid] += v;
    __syncthreads();
  }
  int run = (tid == 0) ? 0 : sums[tid-1];
  for (int i = s; i < e; ++i){ rs[i] = run; run += deg[i]; }
  if (tid == 1023) rs[N] = run;
}

__global__ void k_fill(const int* __restrict__ ei, int E, int N,
                       const int* __restrict__ rs, int* __restrict__ cnt,
                       int* __restrict__ csr_s, int* __restrict__ csr_e){
  int t = blockIdx.x*blockDim.x + threadIdx.x;
  int ET = E + N;
  if (t >= ET) return;
  int src, dst;
  if (t < E){ src = ei[t]; dst = ei[E + t]; } else { src = dst = t - E; }
  int pos = atomicAdd(&cnt[dst], 1);
  int idx = rs[dst] + pos;
  csr_s[idx] = src;
  csr_e[idx] = t;
}

// ---------------- layer 1 GEMM: h1 = x @ W1, plus alpha_s/alpha_d ----------------
__global__ __launch_bounds__(256) void k_gemm1(const float* __restrict__ x, const float* __restrict__ W1,
                                               const float* __restrict__ a1s, const float* __restrict__ a1d,
                                               int N, float* __restrict__ h1,
                                               float* __restrict__ als, float* __restrict__ ald){
  __shared__ float xs[8][128];
  int bn = blockIdx.x * 8;
  int tid = threadIdx.x;
  for (int i = tid; i < 8*128; i += 256){
    int m = i >> 7, k = i & 127;
    int node = bn + m;
    xs[m][k] = (node < N) ? x[(size_t)node*128 + k] : 0.f;
  }
  __syncthreads();
  float acc[8];
  #pragma unroll
  for (int m = 0; m < 8; ++m) acc[m] = 0.f;
  int j = tid;
  for (int k = 0; k < 128; ++k){
    float w = W1[k*256 + j];
    #pragma unroll
    for (int m = 0; m < 8; ++m) acc[m] = fmaf(xs[m][k], w, acc[m]);
  }
  int head = j >> 6;
  int lane = j & 63;
  float cas = a1s[head*64 + lane];
  float cad = a1d[head*64 + lane];
  #pragma unroll
  for (int m = 0; m < 8; ++m){
    int node = bn + m;
    if (node < N) h1[(size_t)node*256 + j] = acc[m];
    float vs = acc[m]*cas, vd = acc[m]*cad;
    #pragma unroll
    for (int o = 32; o; o >>= 1){ vs += __shfl_xor(vs, o, 64); vd += __shfl_xor(vd, o, 64); }
    if (lane == 0 && node < N){ als[node*4+head] = vs; ald[node*4+head] = vd; }
  }
}

// ---------------- layer 2 GEMM: h2 = z1 @ W2, plus alpha2_s/alpha2_d ----------------
__global__ __launch_bounds__(256) void k_gemm2(const float* __restrict__ z1, const float* __restrict__ W2,
                                               const float* __restrict__ a2s, const float* __restrict__ a2d,
                                               int N, float* __restrict__ h2,
                                               float* __restrict__ als, float* __restrict__ ald){
  __shared__ float zs[8][256];
  int bn = blockIdx.x * 8;
  int tid = threadIdx.x;
  for (int i = tid; i < 8*256; i += 256){
    int m = i >> 8, k = i & 255;
    int node = bn + m;
    zs[m][k] = (node < N) ? z1[(size_t)node*256 + k] : 0.f;
  }
  __syncthreads();
  int j = tid & 31;   // out channel
  int m = tid >> 5;   // node in block
  float acc = 0.f;
  for (int k = 0; k < 256; ++k) acc = fmaf(zs[m][k], W2[k*32 + j], acc);
  int node = bn + m;
  int head = j >> 4, lane = j & 15;
  if (node < N) h2[(size_t)node*32 + j] = acc;
  float vs = acc * a2s[head*16 + lane];
  float vd = acc * a2d[head*16 + lane];
  #pragma unroll
  for (int o = 8; o; o >>= 1){ vs += __shfl_xor(vs, o, 64); vd += __shfl_xor(vd, o, 64); }
  if (lane == 0 && node < N){ als[node*2+head] = vs; ald[node*2+head] = vd; }
}

// ---------------- edge kernels ----------------
template<int H>
__global__ void k_edge_a(const int* __restrict__ ei, int E, int N,
                         const float* __restrict__ als, const float* __restrict__ ald,
                         float* __restrict__ eb, unsigned* __restrict__ menc){
  int t = blockIdx.x*blockDim.x + threadIdx.x;
  int ET = E + N;
  if (t >= ET*H) return;
  int eid = t / H, head = t % H;
  int src, dst;
  if (eid < E){ src = ei[eid]; dst = ei[E + eid]; } else { src = dst = eid - E; }
  float el = als[src*H + head] + ald[dst*H + head];
  el = (el > 0.f) ? el : NEG_SLOPE*el;
  eb[t] = el;
  atomicMax(&menc[dst*H + head], fenc(el));
}

template<int H>
__global__ void k_edge_b(const int* __restrict__ ei, int E, int N,
                         const unsigned* __restrict__ menc,
                         float* __restrict__ eb, float* __restrict__ sb){
  int t = blockIdx.x*blockDim.x + threadIdx.x;
  int ET = E + N;
  if (t >= ET*H) return;
  int eid = t / H, head = t % H;
  int dst = (eid < E) ? ei[E + eid] : (eid - E);
  float m = fdec(menc[dst*H + head]);
  float ex = __expf(eb[t] - m);
  eb[t] = ex;
  atomicAdd(&sb[dst*H + head], ex);
}

// ---------------- aggregation ----------------
__global__ __launch_bounds__(256) void k_agg1(const int* __restrict__ rs, const int* __restrict__ csr_s,
                                              const int* __restrict__ csr_e, const float* __restrict__ ex,
                                              const float* __restrict__ sb, const float* __restrict__ h1,
                                              const float* __restrict__ b1, int N, float* __restrict__ z1){
  int node = blockIdx.x;
  int tid = threadIdx.x;
  int head = tid >> 6;
  float inv = 1.0f / (sb[node*4 + head] + EPSV);
  float acc = 0.f;
  int beg = rs[node], end = rs[node+1];
  for (int i = beg; i < end; ++i){
    int src = csr_s[i];
    int eid = csr_e[i];
    float w = ex[eid*4 + head] * inv;
    acc = fmaf(h1[(size_t)src*256 + tid], w, acc);
  }
  float v = acc + b1[tid];
  z1[(size_t)node*256 + tid] = v > 0.f ? v : 0.f;   // fused relu
}

__global__ __launch_bounds__(256) void k_agg2(const int* __restrict__ rs, const int* __restrict__ csr_s,
                                              const int* __restrict__ csr_e, const float* __restrict__ ex,
                                              const float* __restrict__ sb, const float* __restrict__ h2,
                                              const float* __restrict__ b2, int N, float* __restrict__ z2){
  int m = threadIdx.x >> 5;
  int c = threadIdx.x & 31;
  int node = blockIdx.x*8 + m;
  if (node >= N) return;
  int head = c >> 4;
  float inv = 1.0f / (sb[node*2 + head] + EPSV);
  float acc = 0.f;
  int beg = rs[node], end = rs[node+1];
  for (int i = beg; i < end; ++i){
    int src = csr_s[i];
    int eid = csr_e[i];
    acc = fmaf(h2[(size_t)src*32 + c], ex[eid*2 + head]*inv, acc);
  }
  z2[(size_t)node*32 + c] = acc + b2[c];   // no activation after layer 2
}

// ---------------- decode ----------------
__global__ void k_decode(const int* __restrict__ eli, int NQ,
                         const float* __restrict__ z2, float* __restrict__ out){
  int t = blockIdx.x*blockDim.x + threadIdx.x;
  if (t >= NQ*32) return;
  int q = t >> 5, c = t & 31;
  int a = eli[q], b = eli[NQ + q];
  float p = z2[(size_t)a*32 + c] * z2[(size_t)b*32 + c];
  #pragma unroll
  for (int o = 16; o; o >>= 1) p += __shfl_xor(p, o, 64);
  if (c == 0) out[q] = p;
}

extern "C" void kernel_launch(void* const* d_in, const int* in_sizes, int n_in,
                              void* d_out, int out_size, void* d_ws, size_t ws_size,
                              hipStream_t stream) {
  const float* x   = (const float*)d_in[0];
  const int*   ei  = (const int*)d_in[1];
  const int*   eli = (const int*)d_in[2];
  const float* W1  = (const float*)d_in[3];
  const float* a1s = (const float*)d_in[4];
  const float* a1d = (const float*)d_in[5];
  const float* b1  = (const float*)d_in[6];
  const float* W2  = (const float*)d_in[7];
  const float* a2s = (const float*)d_in[8];
  const float* a2d = (const float*)d_in[9];
  const float* b2  = (const float*)d_in[10];
  float* out = (float*)d_out;

  int N  = in_sizes[0] / 128;
  int E  = in_sizes[1] / 2;
  int NQ = in_sizes[2] / 2;
  int ET = E + N;

  char* base = (char*)d_ws;
  size_t off = 0;
  auto alloc = [&](size_t elems)->char*{ char* r = base + off; off += elems*4; return r; };
  int*      deg   = (int*)     alloc(N);
  int*      cnt   = (int*)     alloc(N);
  unsigned* m1    = (unsigned*)alloc((size_t)N*4);
  float*    s1    = (float*)   alloc((size_t)N*4);
  unsigned* m2    = (unsigned*)alloc((size_t)N*2);
  float*    s2    = (float*)   alloc((size_t)N*2);
  size_t zbytes = off;                 // everything above must start zeroed
  int*   rs    = (int*)  alloc(N+1);
  int*   csr_s = (int*)  alloc(ET);
  int*   csr_e = (int*)  alloc(ET);
  float* al1s  = (float*)alloc((size_t)N*4);
  float* al1d  = (float*)alloc((size_t)N*4);
  float* al2s  = (float*)alloc((size_t)N*2);
  float* al2d  = (float*)alloc((size_t)N*2);
  float* e1    = (float*)alloc((size_t)ET*4);
  float* e2    = (float*)alloc((size_t)ET*2);
  float* h1    = (float*)alloc((size_t)N*256);
  float* z1    = (float*)alloc((size_t)N*256);
  float* h2    = (float*)alloc((size_t)N*32);
  float* z2    = (float*)alloc((size_t)N*32);
  (void)ws_size; (void)n_in; (void)out_size;

  hipMemsetAsync(d_ws, 0, zbytes, stream);

  k_deg <<<(ET+255)/256, 256, 0, stream>>>(ei, E, N, deg);
  k_scan<<<1, 1024, 0, stream>>>(deg, N, rs);
  k_fill<<<(ET+255)/256, 256, 0, stream>>>(ei, E, N, rs, cnt, csr_s, csr_e);

  k_gemm1<<<(N+7)/8, 256, 0, stream>>>(x, W1, a1s, a1d, N, h1, al1s, al1d);
  k_edge_a<4><<<((long long)ET*4+255)/256, 256, 0, stream>>>(ei, E, N, al1s, al1d, e1, m1);
  k_edge_b<4><<<((long long)ET*4+255)/256, 256, 0, stream>>>(ei, E, N, m1, e1, s1);
  k_agg1<<<N, 256, 0, stream>>>(rs, csr_s, csr_e, e1, s1, h1, b1, N, z1);

  k_gemm2<<<(N+7)/8, 256, 0, stream>>>(z1, W2, a2s, a2d, N, h2, al2s, al2d);
  k_edge_a<2><<<((long long)ET*2+255)/256, 256, 0, stream>>>(ei, E, N, al2s, al2d, e2, m2);
  k_edge_b<2><<<((long long)ET*2+255)/256, 256, 0, stream>>>(ei, E, N, m2, e2, s2);
  k_agg2<<<(N+7)/8, 256, 0, stream>>>(rs, csr_s, csr_e, e2, s2, h2, b2, N, z2);

  k_decode<<<((long long)NQ*32+255)/256, 256, 0, stream>>>(eli, NQ, z2, out);
}

// Round 5
// 556.298 us; speedup vs baseline: 1.4494x; 1.4494x over previous
//
#include <hip/hip_runtime.h>

#define NEG_SLOPE 0.2f
#define EPSV 1e-16f

// ---------------- CSR build (by dst) ----------------
__global__ void k_deg(const int* __restrict__ ei, int E, int N, int* __restrict__ deg){
  int t = blockIdx.x*blockDim.x + threadIdx.x;
  int ET = E + N;
  if (t >= ET) return;
  int dst = (t < E) ? ei[E + t] : (t - E);
  atomicAdd(&deg[dst], 1);
}

__global__ void k_scan(const int* __restrict__ deg, int N, int* __restrict__ rs){
  __shared__ int sums[1024];
  int tid = threadIdx.x;
  int chunk = (N + 1023) >> 10;
  int s = tid*chunk, e = min(s+chunk, N);
  int sum = 0;
  for (int i = s; i < e; ++i) sum += deg[i];
  sums[tid] = sum;
  __syncthreads();
  for (int off = 1; off < 1024; off <<= 1){
    int v = (tid >= off) ? sums[tid-off] : 0;
    __syncthreads();
    sums[tid] += v;
    __syncthreads();
  }
  int run = (tid == 0) ? 0 : sums[tid-1];
  for (int i = s; i < e; ++i){ rs[i] = run; run += deg[i]; }
  if (tid == 1023) rs[N] = run;
}

__global__ void k_fill(const int* __restrict__ ei, int E, int N,
                       const int* __restrict__ rs, int* __restrict__ cnt,
                       int* __restrict__ csr_s){
  int t = blockIdx.x*blockDim.x + threadIdx.x;
  int ET = E + N;
  if (t >= ET) return;
  int src, dst;
  if (t < E){ src = ei[t]; dst = ei[E + t]; } else { src = dst = t - E; }
  int pos = atomicAdd(&cnt[dst], 1);
  csr_s[rs[dst] + pos] = src;
}

// ---------------- layer 1 GEMM: h1 = x @ W1, plus per-node attention terms ----------------
__global__ __launch_bounds__(256) void k_gemm1(const float* __restrict__ x, const float* __restrict__ W1,
                                               const float* __restrict__ a1s, const float* __restrict__ a1d,
                                               int N, float* __restrict__ h1,
                                               float* __restrict__ als, float* __restrict__ ald){
  __shared__ float xs[8][128];
  int bn = blockIdx.x * 8;
  int tid = threadIdx.x;
  {
    int m = tid >> 5, k4 = tid & 31;       // one float4 per thread
    int node = bn + m;
    float4 v = (node < N) ? ((const float4*)x)[(size_t)node*32 + k4]
                          : make_float4(0.f,0.f,0.f,0.f);
    ((float4*)xs[m])[k4] = v;
  }
  __syncthreads();
  float acc[8];
  #pragma unroll
  for (int m = 0; m < 8; ++m) acc[m] = 0.f;
  int j = tid;
  for (int k = 0; k < 128; ++k){
    float w = W1[k*256 + j];
    #pragma unroll
    for (int m = 0; m < 8; ++m) acc[m] = fmaf(xs[m][k], w, acc[m]);
  }
  int head = j >> 6;
  int lane = j & 63;
  float cas = a1s[head*64 + lane];
  float cad = a1d[head*64 + lane];
  #pragma unroll
  for (int m = 0; m < 8; ++m){
    int node = bn + m;
    if (node < N) h1[(size_t)node*256 + j] = acc[m];
    float vs = acc[m]*cas, vd = acc[m]*cad;
    #pragma unroll
    for (int o = 32; o; o >>= 1){ vs += __shfl_xor(vs, o, 64); vd += __shfl_xor(vd, o, 64); }
    if (lane == 0 && node < N){ als[node*4+head] = vs; ald[node*4+head] = vd; }
  }
}

// ---------------- layer 2 GEMM ----------------
__global__ __launch_bounds__(256) void k_gemm2(const float* __restrict__ z1, const float* __restrict__ W2,
                                               const float* __restrict__ a2s, const float* __restrict__ a2d,
                                               int N, float* __restrict__ h2,
                                               float* __restrict__ als, float* __restrict__ ald){
  __shared__ float zs[8][256];
  int bn = blockIdx.x * 8;
  int tid = threadIdx.x;
  {
    int m = tid >> 6, k4 = tid & 63;       // two float4 per thread
    int node = bn + m;
    const float4 zero = make_float4(0.f,0.f,0.f,0.f);
    ((float4*)zs[m])[k4]      = (node < N)   ? ((const float4*)z1)[(size_t)node*64 + k4] : zero;
    int m2 = m + 4, node2 = bn + m2;
    ((float4*)zs[m2])[k4]     = (node2 < N)  ? ((const float4*)z1)[(size_t)node2*64 + k4] : zero;
  }
  __syncthreads();
  int j = tid & 31;   // out channel
  int m = tid >> 5;   // node in block
  float acc = 0.f;
  for (int k = 0; k < 256; ++k) acc = fmaf(zs[m][k], W2[k*32 + j], acc);
  int node = bn + m;
  int head = j >> 4, lane = j & 15;
  if (node < N) h2[(size_t)node*32 + j] = acc;
  float vs = acc * a2s[head*16 + lane];
  float vd = acc * a2d[head*16 + lane];
  #pragma unroll
  for (int o = 8; o; o >>= 1){ vs += __shfl_xor(vs, o, 64); vd += __shfl_xor(vd, o, 64); }
  if (lane == 0 && node < N){ als[node*2+head] = vs; ald[node*2+head] = vd; }
}

// ---------------- fused softmax + aggregation, layer 1 ----------------
// z1[node][c] = relu( (sum_e ex_e * h1[src_e][c]) / (sum_e ex_e + eps) + b1[c] )
__device__ __forceinline__ float lrelu(float e){ return (e > 0.f) ? e : NEG_SLOPE*e; }

__global__ __launch_bounds__(256) void k_agg1(const int* __restrict__ rs, const int* __restrict__ csr_s,
                                              const float* __restrict__ als, const float* __restrict__ ald,
                                              const float* __restrict__ h1, const float* __restrict__ b1,
                                              int N, float* __restrict__ z1){
  int node = blockIdx.x;
  int tid = threadIdx.x;
  int head = tid >> 6;
  float aldn = ald[node*4 + head];
  int beg = rs[node], end = rs[node+1];
  float acc = 0.f, s = 0.f;
  int i = beg;
  for (; i + 3 < end; i += 4){
    int s0 = csr_s[i], s1 = csr_s[i+1], s2 = csr_s[i+2], s3 = csr_s[i+3];
    float x0 = __expf(lrelu(als[s0*4+head] + aldn));
    float x1 = __expf(lrelu(als[s1*4+head] + aldn));
    float x2 = __expf(lrelu(als[s2*4+head] + aldn));
    float x3 = __expf(lrelu(als[s3*4+head] + aldn));
    float v0 = h1[(size_t)s0*256 + tid];
    float v1 = h1[(size_t)s1*256 + tid];
    float v2 = h1[(size_t)s2*256 + tid];
    float v3 = h1[(size_t)s3*256 + tid];
    acc = fmaf(v0, x0, acc); acc = fmaf(v1, x1, acc);
    acc = fmaf(v2, x2, acc); acc = fmaf(v3, x3, acc);
    s += (x0 + x1) + (x2 + x3);
  }
  for (; i < end; ++i){
    int s0 = csr_s[i];
    float x0 = __expf(lrelu(als[s0*4+head] + aldn));
    acc = fmaf(h1[(size_t)s0*256 + tid], x0, acc);
    s += x0;
  }
  float v = acc / (s + EPSV) + b1[tid];
  z1[(size_t)node*256 + tid] = v > 0.f ? v : 0.f;   // fused relu
}

// ---------------- fused softmax + aggregation, layer 2 ----------------
// 64 lanes per node, 2 edge-slots of 32 lanes; combine with shfl_xor(32).
__global__ __launch_bounds__(256) void k_agg2(const int* __restrict__ rs, const int* __restrict__ csr_s,
                                              const float* __restrict__ als, const float* __restrict__ ald,
                                              const float* __restrict__ h2, const float* __restrict__ b2,
                                              int N, float* __restrict__ z2){
  int tid = threadIdx.x;
  int node = blockIdx.x*4 + (tid >> 6);
  if (node >= N) return;
  int lane = tid & 63;
  int slot = lane >> 5;      // 0/1
  int c    = lane & 31;
  int head = c >> 4;
  float aldn = ald[node*2 + head];
  int beg = rs[node], end = rs[node+1];
  float acc = 0.f, s = 0.f;
  int i = beg + slot;
  for (; i + 2 < end; i += 4){          // edges i and i+2 for this slot
    int s0 = csr_s[i], s1 = csr_s[i+2];
    float x0 = __expf(lrelu(als[s0*2+head] + aldn));
    float x1 = __expf(lrelu(als[s1*2+head] + aldn));
    float v0 = h2[(size_t)s0*32 + c];
    float v1 = h2[(size_t)s1*32 + c];
    acc = fmaf(v0, x0, acc); acc = fmaf(v1, x1, acc);
    s += x0 + x1;
  }
  if (i < end){
    int s0 = csr_s[i];
    float x0 = __expf(lrelu(als[s0*2+head] + aldn));
    acc = fmaf(h2[(size_t)s0*32 + c], x0, acc);
    s += x0;
  }
  acc += __shfl_xor(acc, 32, 64);
  s   += __shfl_xor(s,   32, 64);
  if (slot == 0)
    z2[(size_t)node*32 + c] = acc / (s + EPSV) + b2[c];
}

// ---------------- decode ----------------
__global__ void k_decode(const int* __restrict__ eli, int NQ,
                         const float* __restrict__ z2, float* __restrict__ out){
  int t = blockIdx.x*blockDim.x + threadIdx.x;
  if (t >= NQ*32) return;
  int q = t >> 5, c = t & 31;
  int a = eli[q], b = eli[NQ + q];
  float p = z2[(size_t)a*32 + c] * z2[(size_t)b*32 + c];
  #pragma unroll
  for (int o = 16; o; o >>= 1) p += __shfl_xor(p, o, 64);
  if (c == 0) out[q] = p;
}

extern "C" void kernel_launch(void* const* d_in, const int* in_sizes, int n_in,
                              void* d_out, int out_size, void* d_ws, size_t ws_size,
                              hipStream_t stream) {
  const float* x   = (const float*)d_in[0];
  const int*   ei  = (const int*)d_in[1];
  const int*   eli = (const int*)d_in[2];
  const float* W1  = (const float*)d_in[3];
  const float* a1s = (const float*)d_in[4];
  const float* a1d = (const float*)d_in[5];
  const float* b1  = (const float*)d_in[6];
  const float* W2  = (const float*)d_in[7];
  const float* a2s = (const float*)d_in[8];
  const float* a2d = (const float*)d_in[9];
  const float* b2  = (const float*)d_in[10];
  float* out = (float*)d_out;

  int N  = in_sizes[0] / 128;
  int E  = in_sizes[1] / 2;
  int NQ = in_sizes[2] / 2;
  int ET = E + N;

  char* base = (char*)d_ws;
  size_t off = 0;
  auto alloc = [&](size_t elems)->char*{ char* r = base + off; off += elems*4; return r; };
  int*   deg   = (int*)  alloc(N);
  int*   cnt   = (int*)  alloc(N);
  size_t zbytes = off;                 // only deg+cnt must start zeroed
  int*   rs    = (int*)  alloc(N+1);
  int*   csr_s = (int*)  alloc(ET);
  float* al1s  = (float*)alloc((size_t)N*4);
  float* al1d  = (float*)alloc((size_t)N*4);
  float* al2s  = (float*)alloc((size_t)N*2);
  float* al2d  = (float*)alloc((size_t)N*2);
  float* h1    = (float*)alloc((size_t)N*256);
  float* z1    = (float*)alloc((size_t)N*256);
  float* h2    = (float*)alloc((size_t)N*32);
  float* z2    = (float*)alloc((size_t)N*32);
  (void)ws_size; (void)n_in; (void)out_size;

  hipMemsetAsync(d_ws, 0, zbytes, stream);

  k_deg <<<(ET+255)/256, 256, 0, stream>>>(ei, E, N, deg);
  k_scan<<<1, 1024, 0, stream>>>(deg, N, rs);
  k_fill<<<(ET+255)/256, 256, 0, stream>>>(ei, E, N, rs, cnt, csr_s);

  k_gemm1<<<(N+7)/8, 256, 0, stream>>>(x, W1, a1s, a1d, N, h1, al1s, al1d);
  k_agg1<<<N, 256, 0, stream>>>(rs, csr_s, al1s, al1d, h1, b1, N, z1);

  k_gemm2<<<(N+7)/8, 256, 0, stream>>>(z1, W2, a2s, a2d, N, h2, al2s, al2d);
  k_agg2<<<(N+3)/4, 256, 0, stream>>>(rs, csr_s, al2s, al2d, h2, b2, N, z2);

  k_decode<<<((long long)NQ*32+255)/256, 256, 0, stream>>>(eli, NQ, z2, out);
}

// Round 9
// 540.875 us; speedup vs baseline: 1.4907x; 1.0285x over previous
//
#include <hip/hip_runtime.h>

#define NEG_SLOPE 0.2f
#define EPSV 1e-16f

__device__ __forceinline__ float lrelu(float e){ return (e > 0.f) ? e : NEG_SLOPE*e; }

// ---------------- CSR build (by dst) ----------------
__global__ void k_deg(const int* __restrict__ ei, int E, int N, int* __restrict__ deg){
  int t = blockIdx.x*blockDim.x + threadIdx.x;
  int ET = E + N;
  if (t >= ET) return;
  int dst = (t < E) ? ei[E + t] : (t - E);
  atomicAdd(&deg[dst], 1);
}

__global__ void k_scan(const int* __restrict__ deg, int N, int* __restrict__ rs){
  __shared__ int sums[1024];
  int tid = threadIdx.x;
  int chunk = (N + 1023) >> 10;
  int s = tid*chunk, e = min(s+chunk, N);
  int sum = 0;
  for (int i = s; i < e; ++i) sum += deg[i];
  sums[tid] = sum;
  __syncthreads();
  for (int off = 1; off < 1024; off <<= 1){
    int v = (tid >= off) ? sums[tid-off] : 0;
    __syncthreads();
    sums[tid] += v;
    __syncthreads();
  }
  int run = (tid == 0) ? 0 : sums[tid-1];
  for (int i = s; i < e; ++i){ rs[i] = run; run += deg[i]; }
  if (tid == 1023) rs[N] = run;
}

__global__ void k_fill(const int* __restrict__ ei, int E, int N,
                       const int* __restrict__ rs, int* __restrict__ cnt,
                       int* __restrict__ csr_s){
  int t = blockIdx.x*blockDim.x + threadIdx.x;
  int ET = E + N;
  if (t >= ET) return;
  int src, dst;
  if (t < E){ src = ei[t]; dst = ei[E + t]; } else { src = dst = t - E; }
  int pos = atomicAdd(&cnt[dst], 1);
  csr_s[rs[dst] + pos] = src;
}

// ---------------- layer 1 GEMM: h1 = x @ W1, plus per-node attention terms ----------------
__global__ __launch_bounds__(256) void k_gemm1(const float* __restrict__ x, const float* __restrict__ W1,
                                               const float* __restrict__ a1s, const float* __restrict__ a1d,
                                               int N, float* __restrict__ h1,
                                               float* __restrict__ als, float* __restrict__ ald){
  __shared__ float xs[8][128];
  int bn = blockIdx.x * 8;
  int tid = threadIdx.x;
  {
    int m = tid >> 5, k4 = tid & 31;       // one float4 per thread
    int node = bn + m;
    float4 v = (node < N) ? ((const float4*)x)[(size_t)node*32 + k4]
                          : make_float4(0.f,0.f,0.f,0.f);
    ((float4*)xs[m])[k4] = v;
  }
  __syncthreads();
  float acc[8];
  #pragma unroll
  for (int m = 0; m < 8; ++m) acc[m] = 0.f;
  int j = tid;
  for (int k = 0; k < 128; ++k){
    float w = W1[k*256 + j];
    #pragma unroll
    for (int m = 0; m < 8; ++m) acc[m] = fmaf(xs[m][k], w, acc[m]);
  }
  int head = j >> 6;
  int lane = j & 63;
  float cas = a1s[head*64 + lane];
  float cad = a1d[head*64 + lane];
  #pragma unroll
  for (int m = 0; m < 8; ++m){
    int node = bn + m;
    if (node < N) h1[(size_t)node*256 + j] = acc[m];
    float vs = acc[m]*cas, vd = acc[m]*cad;
    #pragma unroll
    for (int o = 32; o; o >>= 1){ vs += __shfl_xor(vs, o, 64); vd += __shfl_xor(vd, o, 64); }
    if (lane == 0 && node < N){ als[node*4+head] = vs; ald[node*4+head] = vd; }
  }
}

// ---------------- layer 2 GEMM ----------------
__global__ __launch_bounds__(256) void k_gemm2(const float* __restrict__ z1, const float* __restrict__ W2,
                                               const float* __restrict__ a2s, const float* __restrict__ a2d,
                                               int N, float* __restrict__ h2,
                                               float* __restrict__ als, float* __restrict__ ald){
  __shared__ float zs[8][256];
  int bn = blockIdx.x * 8;
  int tid = threadIdx.x;
  {
    int m = tid >> 6, k4 = tid & 63;       // two float4 per thread
    int node = bn + m;
    const float4 zero = make_float4(0.f,0.f,0.f,0.f);
    ((float4*)zs[m])[k4]      = (node < N)   ? ((const float4*)z1)[(size_t)node*64 + k4] : zero;
    int m2 = m + 4, node2 = bn + m2;
    ((float4*)zs[m2])[k4]     = (node2 < N)  ? ((const float4*)z1)[(size_t)node2*64 + k4] : zero;
  }
  __syncthreads();
  int j = tid & 31;   // out channel
  int m = tid >> 5;   // node in block
  float acc = 0.f;
  for (int k = 0; k < 256; ++k) acc = fmaf(zs[m][k], W2[k*32 + j], acc);
  int node = bn + m;
  int head = j >> 4, lane = j & 15;
  if (node < N) h2[(size_t)node*32 + j] = acc;
  float vs = acc * a2s[head*16 + lane];
  float vd = acc * a2d[head*16 + lane];
  #pragma unroll
  for (int o = 8; o; o >>= 1){ vs += __shfl_xor(vs, o, 64); vd += __shfl_xor(vd, o, 64); }
  if (lane == 0 && node < N){ als[node*2+head] = vs; ald[node*2+head] = vd; }
}

// ---------------- fused softmax + aggregation, layer 1 ----------------
// One node per block; 4 waves each own edge stream beg+w, beg+w+4, ...
// Lane l covers channels 4l..4l+3 via float4; cross-wave combine in LDS.
__global__ __launch_bounds__(256) void k_agg1(const int* __restrict__ rs, const int* __restrict__ csr_s,
                                              const float* __restrict__ als, const float* __restrict__ ald,
                                              const float* __restrict__ h1, const float* __restrict__ b1,
                                              int N, float* __restrict__ z1){
  __shared__ float4 accl[4][64];
  __shared__ float  sl[4][64];
  int node = blockIdx.x;
  int tid = threadIdx.x;
  int w = tid >> 6, lane = tid & 63;
  int head = lane >> 4;
  float aldn = ald[node*4 + head];
  int beg = rs[node], end = rs[node+1];
  float4 acc = make_float4(0.f,0.f,0.f,0.f);
  float s = 0.f;
  int i = beg + w;
  for (; i + 4 < end; i += 8){
    int s0 = csr_s[i], s1 = csr_s[i+4];
    float x0 = __expf(lrelu(als[s0*4+head] + aldn));
    float x1 = __expf(lrelu(als[s1*4+head] + aldn));
    float4 v0 = ((const float4*)h1)[(size_t)s0*64 + lane];
    float4 v1 = ((const float4*)h1)[(size_t)s1*64 + lane];
    acc.x = fmaf(v0.x, x0, acc.x); acc.y = fmaf(v0.y, x0, acc.y);
    acc.z = fmaf(v0.z, x0, acc.z); acc.w = fmaf(v0.w, x0, acc.w);
    acc.x = fmaf(v1.x, x1, acc.x); acc.y = fmaf(v1.y, x1, acc.y);
    acc.z = fmaf(v1.z, x1, acc.z); acc.w = fmaf(v1.w, x1, acc.w);
    s += x0 + x1;
  }
  if (i < end){
    int s0 = csr_s[i];
    float x0 = __expf(lrelu(als[s0*4+head] + aldn));
    float4 v0 = ((const float4*)h1)[(size_t)s0*64 + lane];
    acc.x = fmaf(v0.x, x0, acc.x); acc.y = fmaf(v0.y, x0, acc.y);
    acc.z = fmaf(v0.z, x0, acc.z); acc.w = fmaf(v0.w, x0, acc.w);
    s += x0;
  }
  accl[w][lane] = acc;
  sl[w][lane] = s;
  __syncthreads();
  if (tid < 64){
    float4 a0 = accl[0][tid], a1 = accl[1][tid], a2 = accl[2][tid], a3 = accl[3][tid];
    float st = sl[0][tid] + sl[1][tid] + sl[2][tid] + sl[3][tid];
    float inv = 1.0f / (st + EPSV);
    float4 bb = ((const float4*)b1)[tid];
    float4 r;
    r.x = fmaf(a0.x + a1.x + a2.x + a3.x, inv, bb.x);
    r.y = fmaf(a0.y + a1.y + a2.y + a3.y, inv, bb.y);
    r.z = fmaf(a0.z + a1.z + a2.z + a3.z, inv, bb.z);
    r.w = fmaf(a0.w + a1.w + a2.w + a3.w, inv, bb.w);
    r.x = fmaxf(r.x, 0.f); r.y = fmaxf(r.y, 0.f);
    r.z = fmaxf(r.z, 0.f); r.w = fmaxf(r.w, 0.f);
    ((float4*)z1)[(size_t)node*64 + tid] = r;
  }
}

// ---------------- fused softmax + aggregation, layer 2 ----------------
// One node per 64-lane wave: 8 edge slots x 8 lanes (8 lanes x float4 = 128B row).
__global__ __launch_bounds__(256) void k_agg2(const int* __restrict__ rs, const int* __restrict__ csr_s,
                                              const float* __restrict__ als, const float* __restrict__ ald,
                                              const float* __restrict__ h2, const float* __restrict__ b2,
                                              int N, float* __restrict__ z2){
  int tid = threadIdx.x;
  int node = blockIdx.x*4 + (tid >> 6);
  if (node >= N) return;
  int lane = tid & 63;
  int slot = lane >> 3;      // 0..7
  int q    = lane & 7;       // quarter-row: channels q*4..q*4+3
  int head = q >> 2;         // 0 or 1
  float aldn = ald[node*2 + head];
  int beg = rs[node], end = rs[node+1];
  float4 acc = make_float4(0.f,0.f,0.f,0.f);
  float s = 0.f;
  for (int i = beg + slot; i < end; i += 8){
    int s0 = csr_s[i];
    float x0 = __expf(lrelu(als[s0*2+head] + aldn));
    float4 v0 = ((const float4*)h2)[(size_t)s0*8 + q];
    acc.x = fmaf(v0.x, x0, acc.x); acc.y = fmaf(v0.y, x0, acc.y);
    acc.z = fmaf(v0.z, x0, acc.z); acc.w = fmaf(v0.w, x0, acc.w);
    s += x0;
  }
  #pragma unroll
  for (int o = 8; o < 64; o <<= 1){
    acc.x += __shfl_xor(acc.x, o, 64); acc.y += __shfl_xor(acc.y, o, 64);
    acc.z += __shfl_xor(acc.z, o, 64); acc.w += __shfl_xor(acc.w, o, 64);
    s += __shfl_xor(s, o, 64);
  }
  if (slot == 0){
    float inv = 1.0f / (s + EPSV);
    float4 bb = ((const float4*)b2)[q];
    float4 r;
    r.x = fmaf(acc.x, inv, bb.x); r.y = fmaf(acc.y, inv, bb.y);
    r.z = fmaf(acc.z, inv, bb.z); r.w = fmaf(acc.w, inv, bb.w);
    ((float4*)z2)[(size_t)node*8 + q] = r;
  }
}

// ---------------- decode: 8 lanes per query, float4 ----------------
__global__ void k_decode(const int* __restrict__ eli, int NQ,
                         const float* __restrict__ z2, float* __restrict__ out){
  int t = blockIdx.x*blockDim.x + threadIdx.x;
  if (t >= NQ*8) return;
  int qq = t >> 3, q = t & 7;
  int a = eli[qq], b = eli[NQ + qq];
  float4 va = ((const float4*)z2)[(size_t)a*8 + q];
  float4 vb = ((const float4*)z2)[(size_t)b*8 + q];
  float p = va.x*vb.x + va.y*vb.y + va.z*vb.z + va.w*vb.w;
  p += __shfl_xor(p, 1, 64); p += __shfl_xor(p, 2, 64); p += __shfl_xor(p, 4, 64);
  if (q == 0) out[qq] = p;
}

extern "C" void kernel_launch(void* const* d_in, const int* in_sizes, int n_in,
                              void* d_out, int out_size, void* d_ws, size_t ws_size,
                              hipStream_t stream) {
  const float* x   = (const float*)d_in[0];
  const int*   ei  = (const int*)d_in[1];
  const int*   eli = (const int*)d_in[2];
  const float* W1  = (const float*)d_in[3];
  const float* a1s = (const float*)d_in[4];
  const float* a1d = (const float*)d_in[5];
  const float* b1  = (const float*)d_in[6];
  const float* W2  = (const float*)d_in[7];
  const float* a2s = (const float*)d_in[8];
  const float* a2d = (const float*)d_in[9];
  const float* b2  = (const float*)d_in[10];
  float* out = (float*)d_out;

  int N  = in_sizes[0] / 128;
  int E  = in_sizes[1] / 2;
  int NQ = in_sizes[2] / 2;
  int ET = E + N;

  char* base = (char*)d_ws;
  size_t off = 0;
  auto alloc = [&](size_t elems)->char*{ char* r = base + off; off += elems*4; return r; };
  int*   deg   = (int*)  alloc(N);
  int*   cnt   = (int*)  alloc(N);
  size_t zbytes = off;                 // only deg+cnt must start zeroed
  int*   rs    = (int*)  alloc(N+1);
  int*   csr_s = (int*)  alloc(ET);
  float* al1s  = (float*)alloc((size_t)N*4);
  float* al1d  = (float*)alloc((size_t)N*4);
  float* al2s  = (float*)alloc((size_t)N*2);
  float* al2d  = (float*)alloc((size_t)N*2);
  float* h1    = (float*)alloc((size_t)N*256);
  float* z1    = (float*)alloc((size_t)N*256);
  float* h2    = (float*)alloc((size_t)N*32);
  float* z2    = (float*)alloc((size_t)N*32);
  (void)ws_size; (void)n_in; (void)out_size;

  hipMemsetAsync(d_ws, 0, zbytes, stream);

  k_deg <<<(ET+255)/256, 256, 0, stream>>>(ei, E, N, deg);
  k_scan<<<1, 1024, 0, stream>>>(deg, N, rs);
  k_fill<<<(ET+255)/256, 256, 0, stream>>>(ei, E, N, rs, cnt, csr_s);

  k_gemm1<<<(N+7)/8, 256, 0, stream>>>(x, W1, a1s, a1d, N, h1, al1s, al1d);
  k_agg1<<<N, 256, 0, stream>>>(rs, csr_s, al1s, al1d, h1, b1, N, z1);

  k_gemm2<<<(N+7)/8, 256, 0, stream>>>(z1, W2, a2s, a2d, N, h2, al2s, al2d);
  k_agg2<<<(N+3)/4, 256, 0, stream>>>(rs, csr_s, al2s, al2d, h2, b2, N, z2);

  k_decode<<<((long long)NQ*8+255)/256, 256, 0, stream>>>(eli, NQ, z2, out);
}